// Round 3
// baseline (1060.135 us; speedup 1.0000x reference)
//
#include <hip/hip_runtime.h>

typedef __attribute__((ext_vector_type(8))) short bf16x8;
typedef __attribute__((ext_vector_type(4))) float floatx4;
typedef __attribute__((ext_vector_type(16))) float floatx16;
typedef __attribute__((ext_vector_type(4))) unsigned int uintx4;
typedef __attribute__((ext_vector_type(2))) unsigned int uintx2;

#define EPSF 1e-5f
#define RS512 0.04419417382415922f /* 1/sqrt(512) */

__device__ __forceinline__ unsigned short f2bf(float f) {
  unsigned int u = __float_as_uint(f);
  u += 0x7fffu + ((u >> 16) & 1u);
  return (unsigned short)(u >> 16);
}
__device__ __forceinline__ float bf2f(unsigned short s) {
  return __uint_as_float((unsigned int)s << 16);
}

union BFrag { bf16x8 v; int i[4]; unsigned short s[8]; };

// ---------------- Kernel 1: fused qkv conv + BN + PReLU, bf16 emit ----------
// Q: [8][4000][512] token-major; K: [8][4000][512] token-major (pre-scaled by
// 1/sqrt(512)); V: tiled [8][125][512][32] (s-tile-major, d rows of 32 tokens)
#define XSP 1032  /* xs pitch (shorts): 16B-aligned, 2-way-max write banks */
__global__ __launch_bounds__(256) void qkv_kernel(
    const float* __restrict__ x,
    const float* __restrict__ Wq, const float* __restrict__ bq,
    const float* __restrict__ gq, const float* __restrict__ beq,
    const float* __restrict__ mq, const float* __restrict__ vq,
    const float* __restrict__ aq,
    unsigned short* __restrict__ Q, unsigned short* __restrict__ K,
    unsigned short* __restrict__ V) {
  const int b = blockIdx.y;
  const int t0 = blockIdx.x << 4;  // 250 blocks: t0 in [0,4000)
  const int tid = threadIdx.x;

  __shared__ unsigned short xs[16 * XSP];   // [lt][rr] bf16 (~33 KB)
  __shared__ float sW[1536];                // folded qkv weights
  __shared__ float sB[48];                  // folded qkv biases
  __shared__ unsigned short vsm[512 * 18];  // V transpose staging (18 KB)

  // fold BN into conv weights/bias (K additionally scaled by 1/sqrt(512))
  for (int idx = tid; idx < 1536; idx += 256) {
    int n = idx >> 9, ch = (idx >> 5) & 15;
    float inv = gq[n * 16 + ch] * rsqrtf(vq[n * 16 + ch] + EPSF);
    if (n == 1) inv *= RS512;
    sW[idx] = Wq[idx] * inv;
  }
  if (tid < 48) {
    int n = tid >> 4;
    float inv = gq[tid] * rsqrtf(vq[tid] + EPSF);
    float bb = (bq[tid] - mq[tid]) * inv + beq[tid];
    if (n == 1) bb *= RS512;
    sB[tid] = bb;
  }
  {  // stage x[b,:,:,t0..t0+15] into LDS: batched float4 loads (16 in flight)
    const int lt4 = (tid & 3) << 2;
    const int r0 = tid >> 2;
    const float* xb = x + (size_t)b * 4096000 + t0 + lt4;
    float4 xv[16];
#pragma unroll
    for (int p = 0; p < 16; ++p)
      xv[p] = *(const float4*)(xb + (size_t)(r0 + (p << 6)) * 4000);
#pragma unroll
    for (int p = 0; p < 16; ++p) {
      int rr = r0 + (p << 6);
      xs[(lt4 + 0) * XSP + rr] = f2bf(xv[p].x);
      xs[(lt4 + 1) * XSP + rr] = f2bf(xv[p].y);
      xs[(lt4 + 2) * XSP + rr] = f2bf(xv[p].z);
      xs[(lt4 + 3) * XSP + rr] = f2bf(xv[p].w);
    }
  }
  __syncthreads();

  const int lane = tid & 63, wvi = tid >> 6;
  const int c = lane & 15, qd = lane >> 4;
  const int lt = wvi * 4 + qd;
  const int t = t0 + lt;
  const int f0 = (c & 3) * 8;
  const unsigned short* xrow = xs + lt * XSP;
  const float aQ = aq[0], aK = aq[1], aV = aq[2];

  for (int p = 0; p < 4; ++p) {
    const int ch = (c >> 2) + (p << 2);
    float acq[8], ack[8], acv[8];
#pragma unroll
    for (int j = 0; j < 8; ++j) {
      acq[j] = sB[ch]; ack[j] = sB[16 + ch]; acv[j] = sB[32 + ch];
    }
    const float* wqp = sW + ch * 32;
    const float* wkp = sW + 512 + ch * 32;
    const float* wvp = sW + 1024 + ch * 32;
    for (int i = 0; i < 32; ++i) {
      BFrag xf;
      xf.v = *(const bf16x8*)(xrow + i * 32 + f0);
      float wqi = wqp[i], wki = wkp[i], wvi2 = wvp[i];
#pragma unroll
      for (int j = 0; j < 8; ++j) {
        float xv2 = bf2f(xf.s[j]);
        acq[j] += wqi * xv2; ack[j] += wki * xv2; acv[j] += wvi2 * xv2;
      }
    }
    unsigned int qw[4], kw[4];
#pragma unroll
    for (int j2 = 0; j2 < 4; ++j2) {
      float q0 = acq[2 * j2], q1 = acq[2 * j2 + 1];
      q0 = q0 > 0.f ? q0 : aQ * q0; q1 = q1 > 0.f ? q1 : aQ * q1;
      qw[j2] = (unsigned int)f2bf(q0) | ((unsigned int)f2bf(q1) << 16);
      float k0 = ack[2 * j2], k1 = ack[2 * j2 + 1];
      k0 = k0 > 0.f ? k0 : aK * k0; k1 = k1 > 0.f ? k1 : aK * k1;
      kw[j2] = (unsigned int)f2bf(k0) | ((unsigned int)f2bf(k1) << 16);
    }
    const int d0 = (p << 7) + (c << 3);
    uintx4 qv, kv;
    qv[0] = qw[0]; qv[1] = qw[1]; qv[2] = qw[2]; qv[3] = qw[3];
    kv[0] = kw[0]; kv[1] = kw[1]; kv[2] = kw[2]; kv[3] = kw[3];
    *(uintx4*)(Q + (size_t)(b * 4000 + t) * 512 + d0) = qv;
    *(uintx4*)(K + (size_t)(b * 4000 + t) * 512 + d0) = kv;
#pragma unroll
    for (int j = 0; j < 8; ++j) {
      float v0 = acv[j];
      v0 = v0 > 0.f ? v0 : aV * v0;
      vsm[(d0 + j) * 18 + lt] = f2bf(v0);
    }
  }
  __syncthreads();
  {
    const int st = t0 >> 5;
    const int toff = t0 & 16;
    unsigned short* vt = V + ((size_t)(b * 125 + st) * 512) * 32 + toff;
    for (int i = tid; i < 4096; i += 256) {
      int d = i >> 3, u = i & 7;
      unsigned int w2 = *(unsigned int*)&vsm[d * 18 + 2 * u];
      ((unsigned int*)(vt + d * 32))[u] = w2;
    }
  }
}

// ---------------- Kernel 2: 32x32-MFMA sigmoid-attention + enc ConvBlock ----
// 512 threads = 8 waves = 4 pairs; pair owns 32 q-tokens (block = 128).
// Each pair-wave: Q d-half in regs; partial S[32s,32q] over its d-half
// (16 mfma_32x32x16), fp32 partial exchange via LDS, sigmoid, P->LDS bf16;
// PV: d-half split, A=V frags, B=P frags (all 32x32x16). No bpermute.
#define KP 520   /* Ks pitch (shorts) */
#define VP 40    /* Vs pitch */
#define PBP 40   /* Pb pitch */
#define OBP 520  /* Ob pitch */
__global__ __launch_bounds__(512, 2) void attn_kernel(
    const float* __restrict__ x,
    const float* __restrict__ encW, const float* __restrict__ encb,
    const float* __restrict__ encg, const float* __restrict__ encbe,
    const float* __restrict__ encm, const float* __restrict__ encv,
    const float* __restrict__ enca,
    const unsigned short* __restrict__ Q, const unsigned short* __restrict__ K,
    const unsigned short* __restrict__ V, float* __restrict__ out) {
  const int tid = threadIdx.x;
  const int lane = tid & 63;
  const int w = tid >> 6;
  const int pair = w >> 1, ph = w & 1;     // ph = d-half this wave owns
  const int b = blockIdx.x >> 5;           // 8 b x 32 tiles
  const int bt0 = (blockIdx.x & 31) << 7;  // 0..3968
  const int t0p = bt0 + (pair << 5);       // pair's 32-token base
  const bool pact = t0p < 4000;
  const int tq = lane & 31;                // token / matrix-row lane index
  const int hh = lane >> 5;                // k-half within frags

  __shared__ union {
    struct {
      unsigned short Ks[32 * KP];       // 66560 B
      unsigned short Vs[512 * VP];      // 40960 B
      unsigned short Pb[4 * 32 * PBP];  // 10240 B
      float Pex[8 * 4 * 64 * 4];        // 32768 B  [wave][quad][lane][4]
    } lp;
    unsigned short Ob[4 * 32 * OBP];    // 133120 B  [pair][t][d]
  } sm;

  // Q fragments: B-operand, d-half of this wave; token = t0p + tq
  bf16x8 qf[16];
  {
    const int t = pact ? (t0p + tq) : 0;
    const unsigned short* qp =
        Q + (size_t)(b * 4000 + t) * 512 + (ph << 8) + (hh << 3);
#pragma unroll
    for (int ch = 0; ch < 16; ++ch) qf[ch] = *(const bf16x8*)(qp + (ch << 4));
  }

  floatx16 zero16;
#pragma unroll
  for (int i = 0; i < 16; ++i) zero16[i] = 0.f;
  floatx16 acc[8];
#pragma unroll
  for (int dt = 0; dt < 8; ++dt) acc[dt] = zero16;

  const unsigned short* Kb = K + (size_t)b * 4000 * 512;
  const unsigned short* Vb = V + (size_t)b * 125 * 16384;

  // prefetch tile 0
  uintx4 kpre[4], vpre[4];
#pragma unroll
  for (int j = 0; j < 4; ++j) {
    int id = tid + (j << 9);
    kpre[j] = *(const uintx4*)(Kb + (size_t)id * 8);
    vpre[j] = *(const uintx4*)(Vb + (size_t)id * 8);
  }

#pragma unroll 1
  for (int it = 0; it < 125; ++it) {
    __syncthreads();  // b1: prev-iter LDS reads done
#pragma unroll
    for (int j = 0; j < 4; ++j) {
      int id = tid + (j << 9);
      *(uintx4*)(sm.lp.Ks + (id >> 6) * KP + (id & 63) * 8) = kpre[j];
      *(uintx4*)(sm.lp.Vs + (id >> 2) * VP + (id & 3) * 8) = vpre[j];
    }
    __syncthreads();  // b2: tiles staged
    const int nit = (it + 1 < 125) ? it + 1 : it;
    {  // K prefetch for next tile (in flight across S phase)
      const unsigned short* kg = Kb + (size_t)nit * 16384;
#pragma unroll
      for (int j = 0; j < 4; ++j)
        kpre[j] = *(const uintx4*)(kg + (size_t)(tid + (j << 9)) * 8);
    }
    floatx16 sp = zero16;
    if (pact) {  // partial S over this wave's d-half
      const unsigned short* kp = sm.lp.Ks + tq * KP + (ph << 8) + (hh << 3);
#pragma unroll
      for (int ch = 0; ch < 16; ++ch) {
        bf16x8 kf = *(const bf16x8*)(kp + (ch << 4));
        sp = __builtin_amdgcn_mfma_f32_32x32x16_bf16(kf, qf[ch], sp, 0, 0, 0);
      }
      float* pw = sm.lp.Pex + (w << 10);
#pragma unroll
      for (int q = 0; q < 4; ++q) {
        floatx4 v4;
        v4[0] = sp[4 * q]; v4[1] = sp[4 * q + 1];
        v4[2] = sp[4 * q + 2]; v4[3] = sp[4 * q + 3];
        *(floatx4*)(pw + (((q << 6) + lane) << 2)) = v4;
      }
    }
    __syncthreads();  // b3: partials visible
    {  // V prefetch for next tile (in flight across PV phase)
      const unsigned short* vg = Vb + (size_t)nit * 16384;
#pragma unroll
      for (int j = 0; j < 4; ++j)
        vpre[j] = *(const uintx4*)(vg + (size_t)(tid + (j << 9)) * 8);
    }
    if (pact) {
      const float* pr = sm.lp.Pex + ((w ^ 1) << 10);
#pragma unroll
      for (int q = 0; q < 4; ++q) {
        floatx4 pp = *(const floatx4*)(pr + (((q << 6) + lane) << 2));
        sp[4 * q] += pp[0]; sp[4 * q + 1] += pp[1];
        sp[4 * q + 2] += pp[2]; sp[4 * q + 3] += pp[3];
      }
      // sigmoid + write this wave's s-half of P (quads 2*ph, 2*ph+1)
#pragma unroll
      for (int u = 0; u < 2; ++u) {
        const int qq = (ph << 1) + u;
        float p0 = __builtin_amdgcn_rcpf(1.f + __expf(-sp[4 * qq]));
        float p1 = __builtin_amdgcn_rcpf(1.f + __expf(-sp[4 * qq + 1]));
        float p2 = __builtin_amdgcn_rcpf(1.f + __expf(-sp[4 * qq + 2]));
        float p3 = __builtin_amdgcn_rcpf(1.f + __expf(-sp[4 * qq + 3]));
        uintx2 pk;
        pk[0] = (unsigned int)f2bf(p0) | ((unsigned int)f2bf(p1) << 16);
        pk[1] = (unsigned int)f2bf(p2) | ((unsigned int)f2bf(p3) << 16);
        const int srow = (qq << 3) + (hh << 2);  // s = srow + 0..3
        *(uintx2*)(sm.lp.Pb + pair * 1280 + tq * PBP + srow) = pk;
      }
    }
    __syncthreads();  // b4: P visible
    if (pact) {
      const unsigned short* pb = sm.lp.Pb + pair * 1280 + tq * PBP + (hh << 3);
      bf16x8 pf0 = *(const bf16x8*)(pb);
      bf16x8 pf1 = *(const bf16x8*)(pb + 16);
      const unsigned short* vp = sm.lp.Vs + ((ph << 8) + tq) * VP + (hh << 3);
#pragma unroll
      for (int dt = 0; dt < 8; ++dt) {
        bf16x8 vf0 = *(const bf16x8*)(vp + dt * 32 * VP);
        bf16x8 vf1 = *(const bf16x8*)(vp + dt * 32 * VP + 16);
        acc[dt] = __builtin_amdgcn_mfma_f32_32x32x16_bf16(vf0, pf0, acc[dt], 0, 0, 0);
        acc[dt] = __builtin_amdgcn_mfma_f32_32x32x16_bf16(vf1, pf1, acc[dt], 0, 0, 0);
      }
    }
  }

  // ---- epilogue: O (bf16) -> LDS redistribution -> fused enc conv + res ----
  __syncthreads();  // loop LDS dead; reuse as Ob
  if (pact) {
#pragma unroll
    for (int dt = 0; dt < 8; ++dt) {
#pragma unroll
      for (int q = 0; q < 4; ++q) {
        const int d = (ph << 8) + (dt << 5) + (q << 3) + (hh << 2);
        uintx2 pk;
        pk[0] = (unsigned int)f2bf(acc[dt][4 * q]) |
                ((unsigned int)f2bf(acc[dt][4 * q + 1]) << 16);
        pk[1] = (unsigned int)f2bf(acc[dt][4 * q + 2]) |
                ((unsigned int)f2bf(acc[dt][4 * q + 3]) << 16);
        *(uintx2*)(sm.Ob + pair * (32 * OBP) + tq * OBP + d) = pk;
      }
    }
  }
  __syncthreads();
  {
    const int opair = w >> 1, ohalf = w & 1;
    const int tb = bt0 + (opair << 5) + (ohalf << 4);
    if (tb < 4000) {
      const int tl = lane & 15, fg = lane >> 4;
      const unsigned short* ob =
          sm.Ob + opair * (32 * OBP) + ((ohalf << 4) + tl) * OBP + (fg << 3);
      float r[16][8];
#pragma unroll
      for (int ch = 0; ch < 16; ++ch) {
        BFrag ov;
        ov.v = *(const bf16x8*)(ob + (ch << 5));
#pragma unroll
        for (int j = 0; j < 8; ++j) r[ch][j] = bf2f(ov.s[j]);
      }
      const float ealpha = enca[0];
      const int t_abs = tb + tl;
#pragma unroll 1
      for (int o = 0; o < 32; ++o) {
        const float inv = encg[o] * rsqrtf(encv[o] + EPSF);
        const float bfo = (encb[o] - encm[o]) * inv + encbe[o];
        float wr[16];
#pragma unroll
        for (int i = 0; i < 16; ++i) wr[i] = encW[o * 16 + i] * inv;
        const size_t obase = ((size_t)((b << 5) + o) * 32 + (fg << 3)) * 4000 + t_abs;
#pragma unroll
        for (int j = 0; j < 8; ++j) {
          float e = bfo;
#pragma unroll
          for (int i = 0; i < 16; ++i) e += wr[i] * r[i][j];
          e = e > 0.f ? e : ealpha * e;
          out[obase + (size_t)j * 4000] = e + x[obase + (size_t)j * 4000];
        }
      }
    }
  }
}

extern "C" void kernel_launch(void* const* d_in, const int* in_sizes, int n_in,
                              void* d_out, int out_size, void* d_ws,
                              size_t ws_size, hipStream_t stream) {
  const float* x = (const float*)d_in[0];
  unsigned short* Q = (unsigned short*)d_ws;
  unsigned short* K = Q + (size_t)8 * 4000 * 512;
  unsigned short* V = K + (size_t)8 * 4000 * 512;

  dim3 g1(250, 8);
  qkv_kernel<<<g1, 256, 0, stream>>>(
      x, (const float*)d_in[1], (const float*)d_in[2], (const float*)d_in[3],
      (const float*)d_in[4], (const float*)d_in[5], (const float*)d_in[6],
      (const float*)d_in[7], Q, K, V);

  attn_kernel<<<dim3(256), 512, 0, stream>>>(
      x, (const float*)d_in[8], (const float*)d_in[9], (const float*)d_in[10],
      (const float*)d_in[11], (const float*)d_in[12], (const float*)d_in[13],
      (const float*)d_in[14], Q, K, V, (float*)d_out);
}